// Round 16
// baseline (881.597 us; speedup 1.0000x reference)
//
#include <hip/hip_runtime.h>
#include <hip/hip_fp16.h>
#include <math.h>

#define N_NODES 50000
#define N_EDG   800000
#define NH      8
#define DH      32
#define HID     256
#define MAXD    64    // fixed slots/node; P(in-deg>64 | Poisson(16)) ~ 1e-19
#define EPB     4096  // edges per fill block (256 thr x 16)
#define PROJ_FB 150   // fill blocks per y in proj union (x2 y = 1,228,800 edges, ~51%)
#define PROJ_EB (300*EPB)
#define G3_FB   48    // fill blocks per (y,z) in gemm3-l0 union (x6 = 1,179,648 >= rest)
#define AGGB    12500 // agg blocks per path (4 nodes/block)

typedef __attribute__((ext_vector_type(8))) short bf16x8;
typedef __attribute__((ext_vector_type(4))) float f32x4;

// direct global->LDS, 16B/lane: dst must be wave-uniform base (HW adds
// lane*16B); source address is per-lane (carries the swizzle).
#define GLL16(src, dst) __builtin_amdgcn_global_load_lds(                  \
    (const __attribute__((address_space(1))) void*)(const void*)(src),     \
    (__attribute__((address_space(3))) void*)(dst), 16, 0, 0)

__device__ __forceinline__ unsigned short f2bf(float x) {
    unsigned u = __float_as_uint(x);
    u += 0x7FFF + ((u >> 16) & 1);          // RNE
    return (unsigned short)(u >> 16);
}
__device__ __forceinline__ float bf2f(unsigned short h) {
    return __uint_as_float(((unsigned)h) << 16);
}
// packed f32 pair -> 2x bf16 (RNE, bit-identical to f2bf; inline asm)
__device__ __forceinline__ unsigned cvtpk_bf16(float a, float b) {
    unsigned r;
    asm("v_cvt_pk_bf16_f32 %0, %1, %2" : "=v"(r) : "v"(a), "v"(b));
    return r;
}
__device__ __forceinline__ float fastrcp(float x) {
    float r;
    asm("v_rcp_f32 %0, %1" : "=v"(r) : "v"(x));
    return r;
}
// 8 f32 -> bf16 hi/lo planes, cvt_pk based
__device__ __forceinline__ void split8(const float4& a, const float4& b,
                                       uint4& hi, uint4& lo) {
    float f[8] = {a.x,a.y,a.z,a.w,b.x,b.y,b.z,b.w};
    unsigned hpk[4], lpk[4];
    #pragma unroll
    for (int i = 0; i < 4; ++i) {
        hpk[i] = cvtpk_bf16(f[2*i], f[2*i+1]);
        float hl = __uint_as_float(hpk[i] << 16);           // bf2f(lo half)
        float hh = __uint_as_float(hpk[i] & 0xffff0000u);   // bf2f(hi half)
        lpk[i] = cvtpk_bf16(f[2*i] - hl, f[2*i+1] - hh);
    }
    hi = make_uint4(hpk[0], hpk[1], hpk[2], hpk[3]);
    lo = make_uint4(lpk[0], lpk[1], lpk[2], lpk[3]);
}
// 8 fp16 -> bf16 hi/lo planes (EXACT split)
__device__ __forceinline__ void h8_to_pair(uint4 r, uint4& hi, uint4& lo) {
    const __half2* hp = (const __half2*)&r;
    unsigned hpk[4], lpk[4];
    #pragma unroll
    for (int i = 0; i < 4; ++i) {
        float2 f = __half22float2(hp[i]);
        hpk[i] = cvtpk_bf16(f.x, f.y);
        float hl = __uint_as_float(hpk[i] << 16);
        float hh = __uint_as_float(hpk[i] & 0xffff0000u);
        lpk[i] = cvtpk_bf16(f.x - hl, f.y - hh);
    }
    hi = make_uint4(hpk[0], hpk[1], hpk[2], hpk[3]);
    lo = make_uint4(lpk[0], lpk[1], lpk[2], lpk[3]);
}

// fused f16->f32 convert + FMA (bit-identical to cvt+fma, 1 VALU op)
__device__ __forceinline__ void fmix2(float& alo, float& ahi, unsigned rv, float w) {
    asm("v_fma_mix_f32 %0, %1, %2, %0 op_sel:[0,0,0] op_sel_hi:[1,0,0]"
        : "+v"(alo) : "v"(rv), "v"(w));
    asm("v_fma_mix_f32 %0, %1, %2, %0 op_sel:[1,0,0] op_sel_hi:[1,0,0]"
        : "+v"(ahi) : "v"(rv), "v"(w));
}

// ---- adjacency-build worker (far-end throughput-bound; rides GEMMs.
// Fill blocks at LOW blockIdx.x so the wall starts at t=0. R16: split
// rebalanced ~51/49 between the two unions (l0 union interferes ~1.6x
// with its GEMM; proj union's GEMM is small so its wall runs cleanly).
__device__ __forceinline__ void fill_edges(const int* __restrict__ edges,
                                           int* __restrict__ cnt3,
                                           unsigned short* __restrict__ slots3,
                                           int fb, int ebase) {
    const int base = ebase + fb * EPB + (int)threadIdx.x;
    #pragma unroll 1
    for (int t = 0; t < 4; ++t) {
        int dd[4], ss[4];
        #pragma unroll
        for (int j = 0; j < 4; ++j) {
            int e = base + (t * 4 + j) * 256;
            if (e < 3 * N_EDG) {
                int p = e / N_EDG, i = e - p * N_EDG;
                const int* src = edges + (size_t)p * 2 * N_EDG;
                int s = src[i], d = src[N_EDG + i];
                ss[j] = min(max(s, 0), N_NODES - 1);
                dd[j] = p * N_NODES + min(max(d, 0), N_NODES - 1);
            } else { ss[j] = -1; dd[j] = 0; }
        }
        int pos[4];
        #pragma unroll
        for (int j = 0; j < 4; ++j)
            if (ss[j] >= 0) pos[j] = atomicAdd(&cnt3[dd[j]], 1);
        #pragma unroll
        for (int j = 0; j < 4; ++j)
            if (ss[j] >= 0 && pos[j] < MAXD)
                slots3[(size_t)dd[j] * MAXD + pos[j]] = (unsigned short)ss[j];
    }
}

// ---- segment-softmax aggregation worker (R6 form; fabric-bound ~4 TB/s).
__device__ __forceinline__ void agg_worker(
    int fb, int p, int l,
    const int* __restrict__ cnt3, const unsigned short* __restrict__ slots3,
    const float* __restrict__ ssrc3, const float* __restrict__ sdst3,
    const __half* __restrict__ hp3, const float* __restrict__ gatB,
    __half* __restrict__ emb16) {
    const int wid  = fb * 4 + ((int)threadIdx.x >> 6);
    const int lane = threadIdx.x & 63;
    if (wid >= N_NODES) return;
    const int n = wid;
    const unsigned short* srcs = slots3 + ((size_t)p * N_NODES + n) * MAXD;
    const float* s_src = ssrc3 + p * N_NODES * NH;
    const float* s_dst = sdst3 + p * N_NODES * NH;
    const __half* hp = hp3 + (size_t)p * N_NODES * HID;
    const float* bias = gatB + (2*p + l) * HID;
    const int deg = min(cnt3[p * N_NODES + n], MAXD);

    const int sub = lane & 31, eo = lane >> 5;
    const int h2  = sub >> 2;
    const float sd2 = s_dst[n*NH + h2];
    const uint4* hp4 = (const uint4*)hp;
    float dn = 0.f;
    float a0=0.f,a1=0.f,a2=0.f,a3=0.f,a4=0.f,a5=0.f,a6=0.f,a7=0.f;

    int i = eo;
    for (; i + 6 < deg; i += 8) {
        const int s0 = srcs[i];
        const int s1 = srcs[i + 2];
        const int s2 = srcs[i + 4];
        const int s3 = srcs[i + 6];
        const float x0 = s_src[s0*NH + h2];
        const float x1 = s_src[s1*NH + h2];
        const float x2 = s_src[s2*NH + h2];
        const float x3 = s_src[s3*NH + h2];
        const uint4 r0 = hp4[s0*32 + sub];
        const uint4 r1 = hp4[s1*32 + sub];
        const uint4 r2 = hp4[s2*32 + sub];
        const uint4 r3 = hp4[s3*32 + sub];
        float e0 = x0 + sd2; e0 = e0 > 0.f ? e0 : 0.2f * e0;
        float e1 = x1 + sd2; e1 = e1 > 0.f ? e1 : 0.2f * e1;
        float e2 = x2 + sd2; e2 = e2 > 0.f ? e2 : 0.2f * e2;
        float e3 = x3 + sd2; e3 = e3 > 0.f ? e3 : 0.2f * e3;
        const float w0 = __expf(e0), w1 = __expf(e1);
        const float w2 = __expf(e2), w3 = __expf(e3);
        dn += w0; dn += w1; dn += w2; dn += w3;
        fmix2(a0, a1, r0.x, w0); fmix2(a2, a3, r0.y, w0);
        fmix2(a4, a5, r0.z, w0); fmix2(a6, a7, r0.w, w0);
        fmix2(a0, a1, r1.x, w1); fmix2(a2, a3, r1.y, w1);
        fmix2(a4, a5, r1.z, w1); fmix2(a6, a7, r1.w, w1);
        fmix2(a0, a1, r2.x, w2); fmix2(a2, a3, r2.y, w2);
        fmix2(a4, a5, r2.z, w2); fmix2(a6, a7, r2.w, w2);
        fmix2(a0, a1, r3.x, w3); fmix2(a2, a3, r3.y, w3);
        fmix2(a4, a5, r3.z, w3); fmix2(a6, a7, r3.w, w3);
    }
    for (; i + 2 < deg; i += 4) {
        const int s0 = srcs[i];
        const int s1 = srcs[i + 2];
        const float x0 = s_src[s0*NH + h2];
        const float x1 = s_src[s1*NH + h2];
        const uint4 r0 = hp4[s0*32 + sub];
        const uint4 r1 = hp4[s1*32 + sub];
        float e0 = x0 + sd2; e0 = e0 > 0.f ? e0 : 0.2f * e0;
        float e1 = x1 + sd2; e1 = e1 > 0.f ? e1 : 0.2f * e1;
        const float w0 = __expf(e0), w1 = __expf(e1);
        dn += w0; dn += w1;
        fmix2(a0, a1, r0.x, w0); fmix2(a2, a3, r0.y, w0);
        fmix2(a4, a5, r0.z, w0); fmix2(a6, a7, r0.w, w0);
        fmix2(a0, a1, r1.x, w1); fmix2(a2, a3, r1.y, w1);
        fmix2(a4, a5, r1.z, w1); fmix2(a6, a7, r1.w, w1);
    }
    if (i < deg) {
        const int s0 = srcs[i];
        const float x0 = s_src[s0*NH + h2];
        const uint4 r0 = hp4[s0*32 + sub];
        float e0 = x0 + sd2; e0 = e0 > 0.f ? e0 : 0.2f * e0;
        const float w0 = __expf(e0);
        dn += w0;
        fmix2(a0, a1, r0.x, w0); fmix2(a2, a3, r0.y, w0);
        fmix2(a4, a5, r0.z, w0); fmix2(a6, a7, r0.w, w0);
    }
    dn += __shfl_xor(dn, 32);
    a0 += __shfl_xor(a0, 32); a1 += __shfl_xor(a1, 32);
    a2 += __shfl_xor(a2, 32); a3 += __shfl_xor(a3, 32);
    a4 += __shfl_xor(a4, 32); a5 += __shfl_xor(a5, 32);
    a6 += __shfl_xor(a6, 32); a7 += __shfl_xor(a7, 32);
    if (lane < 32) {
        float evs = s_src[n*NH + h2] + sd2;
        evs = evs > 0.f ? evs : 0.2f * evs;
        float ws = __expf(evs);
        dn += ws;
        const uint4 rs = hp4[n*32 + sub];
        fmix2(a0, a1, rs.x, ws); fmix2(a2, a3, rs.y, ws);
        fmix2(a4, a5, rs.z, ws); fmix2(a6, a7, rs.w, ws);

        float rdn = fastrcp(dn);
        float v[8] = {a0,a1,a2,a3,a4,a5,a6,a7};
        const float4 b0 = *(const float4*)&bias[sub*8];
        const float4 b1 = *(const float4*)&bias[sub*8 + 4];
        v[0]=v[0]*rdn+b0.x; v[1]=v[1]*rdn+b0.y; v[2]=v[2]*rdn+b0.z; v[3]=v[3]*rdn+b0.w;
        v[4]=v[4]*rdn+b1.x; v[5]=v[5]*rdn+b1.y; v[6]=v[6]*rdn+b1.z; v[7]=v[7]*rdn+b1.w;
        unsigned short hh[8];
        #pragma unroll
        for (int k = 0; k < 8; ++k) {
            float e = v[k] > 0.f ? v[k] : (__expf(v[k]) - 1.f);   // ELU
            hh[k] = __half_as_ushort(__float2half(e));
        }
        size_t o = ((size_t)p * N_NODES + n) * HID + sub * 8;   // path-major
        *(uint4*)&emb16[o] = make_uint4(hh[0]|((unsigned)hh[1]<<16), hh[2]|((unsigned)hh[3]<<16),
                                        hh[4]|((unsigned)hh[5]<<16), hh[6]|((unsigned)hh[7]<<16));
    }
}

// standalone agg: grid (AGGB, 3), blockIdx.y = path. 0 LDS -> 78% occupancy.
__global__ __launch_bounds__(256)
void agg3y_k(const int* __restrict__ cnt3, const unsigned short* __restrict__ slots3,
             const float* __restrict__ ssrc3, const float* __restrict__ sdst3,
             const __half* __restrict__ hp3, const float* __restrict__ gatB,
             int l, __half* __restrict__ emb16) {
    agg_worker(blockIdx.x, blockIdx.y, l, cnt3, slots3, ssrc3, sdst3, hp3, gatB, emb16);
}

// ================= bf16x3 MFMA GEMM, single =============================
// FILL=1: blocks bx < PROJ_FB run fill_edges FIRST (wall starts at t=0).
// AMODE: 0 f32 A, 1 fp16 A, 3 on-the-fly z with INLINE softmax of raw
//        semantic scores (w4z holds raw sc[n*4+p]).
// OUTMODE: 0 f32, 2 fp16, 3 fused relu+logits (out[n][2]),
//          4 fused tanh+semscore dot (writes sc[n*4+z]).
template<int NC, int ACT, int OUTMODE, int AMODE, int FILL>
__global__ __launch_bounds__(256)
void mfma_gemm_k(const float* __restrict__ A32p, const __half* __restrict__ A16p,
                 int lda,
                 const unsigned short* __restrict__ WThi,
                 const unsigned short* __restrict__ WTlo,
                 const float* __restrict__ bias,
                 float* __restrict__ C, __half* __restrict__ Ch,
                 int ldc, int M, int K,
                 const int* __restrict__ edges, int* __restrict__ cnt3,
                 unsigned short* __restrict__ slots3,
                 const float* __restrict__ w4z,
                 int aplanez, int cplanez,
                 const float* __restrict__ logW2, const float* __restrict__ logB2) {
    __shared__ unsigned short sAh[128*32], sAl[128*32], sBh[128*32], sBl[128*32];
    if constexpr (FILL) {
        if ((int)blockIdx.x < PROJ_FB) {
            fill_edges(edges, cnt3, slots3,
                       (int)blockIdx.x + PROJ_FB * (int)blockIdx.y, 0);
            return;
        }
    }
    const int bx0 = FILL ? ((int)blockIdx.x - PROJ_FB) : (int)blockIdx.x;
    if (A16p) A16p += (size_t)blockIdx.z * aplanez;
    if (C)    C    += (size_t)blockIdx.z * cplanez;
    const int tid  = threadIdx.x;
    const int lane = tid & 63;
    const int w    = tid >> 6;
    const int wr   = w >> 1, wc = w & 1;
    const int r0   = bx0 * 128;
    const int c0   = blockIdx.y * 128;
    const int l15  = lane & 15, q = lane >> 4;

    const int cl8   = (((lane & 3) ^ ((lane >> 4) & 3)) << 3);
    const int lrow  = w*32 + (lane >> 2);
    const int gbrow0 = c0 + lrow, gbrow1 = c0 + lrow + 16;
    const int lbase = w * 1024;                 // shorts (wave-uniform)

    const int srow = tid >> 2, slot = tid & 3;
    const int arow0 = min(r0 + srow,      M - 1);
    const int arow1 = min(r0 + srow + 64, M - 1);
    const size_t ga0 = (size_t)arow0 * lda + slot * 8;
    const size_t ga1 = (size_t)arow1 * lda + slot * 8;
    const int lda0 = srow*32 + ((slot ^ ((srow >> 2) & 3)) << 3);
    const int lda1 = lda0 + 64*32;

    float4 w0r, w1r;
    if constexpr (AMODE == 3) {
        // raw scores -> inline 3-way softmax
        float4 s0v = *(const float4*)&w4z[arow0 * 4];
        float4 s1v = *(const float4*)&w4z[arow1 * 4];
        float m0 = fmaxf(s0v.x, fmaxf(s0v.y, s0v.z));
        float m1 = fmaxf(s1v.x, fmaxf(s1v.y, s1v.z));
        float e00 = __expf(s0v.x-m0), e01 = __expf(s0v.y-m0), e02 = __expf(s0v.z-m0);
        float e10 = __expf(s1v.x-m1), e11 = __expf(s1v.y-m1), e12 = __expf(s1v.z-m1);
        float r0s = fastrcp(e00+e01+e02), r1s = fastrcp(e10+e11+e12);
        w0r = make_float4(e00*r0s, e01*r0s, e02*r0s, 0.f);
        w1r = make_float4(e10*r1s, e11*r1s, e12*r1s, 0.f);
    }

    f32x4 acc[4][4];
    #pragma unroll
    for (int i = 0; i < 4; ++i)
        #pragma unroll
        for (int j = 0; j < 4; ++j) acc[i][j] = (f32x4){0.f, 0.f, 0.f, 0.f};

    const int swzF = (l15 >> 2) & 3;
    const int qs   = ((q ^ swzF) << 3);

    const int nsteps = K >> 5;
    for (int s = 0; s < nsteps; ++s) {
        const int kc = s << 5;
        __syncthreads();
        // B: direct global->LDS, in flight under the A conversion below
        GLL16(&WThi[(size_t)gbrow0*K + kc + cl8], &sBh[lbase]);
        GLL16(&WThi[(size_t)gbrow1*K + kc + cl8], &sBh[lbase + 512]);
        GLL16(&WTlo[(size_t)gbrow0*K + kc + cl8], &sBl[lbase]);
        GLL16(&WTlo[(size_t)gbrow1*K + kc + cl8], &sBl[lbase + 512]);
        uint4 h0, l0, h1, l1;
        if constexpr (AMODE == 0) {
            float4 f0a = *(const float4*)&A32p[ga0 + kc];
            float4 f0b = *(const float4*)&A32p[ga0 + kc + 4];
            float4 f1a = *(const float4*)&A32p[ga1 + kc];
            float4 f1b = *(const float4*)&A32p[ga1 + kc + 4];
            split8(f0a, f0b, h0, l0);
            split8(f1a, f1b, h1, l1);
        } else if constexpr (AMODE == 1) {
            uint4 r0v = *(const uint4*)&A16p[ga0 + kc];
            uint4 r1v = *(const uint4*)&A16p[ga1 + kc];
            h8_to_pair(r0v, h0, l0);
            h8_to_pair(r1v, h1, l1);
        } else {   // AMODE == 3
            const int off = kc + slot * 8;
            #pragma unroll
            for (int rr = 0; rr < 2; ++rr) {
                const int row = rr ? arow1 : arow0;
                const float4 wv = rr ? w1r : w0r;
                const __half2* e0 = (const __half2*)&A16p[(size_t)row * HID + off];
                const __half2* e1 = (const __half2*)&A16p[((size_t)N_NODES + row) * HID + off];
                const __half2* e2 = (const __half2*)&A16p[((size_t)2*N_NODES + row) * HID + off];
                float vv[8];
                #pragma unroll
                for (int j2 = 0; j2 < 4; ++j2) {
                    float2 fa = __half22float2(e0[j2]);
                    float2 fb2 = __half22float2(e1[j2]);
                    float2 fc = __half22float2(e2[j2]);
                    vv[2*j2]   = wv.x*fa.x + wv.y*fb2.x + wv.z*fc.x;
                    vv[2*j2+1] = wv.x*fa.y + wv.y*fb2.y + wv.z*fc.y;
                }
                if (rr) split8(*(const float4*)&vv[0], *(const float4*)&vv[4], h1, l1);
                else    split8(*(const float4*)&vv[0], *(const float4*)&vv[4], h0, l0);
            }
        }
        *(uint4*)&sAh[lda0] = h0; *(uint4*)&sAl[lda0] = l0;
        *(uint4*)&sAh[lda1] = h1; *(uint4*)&sAl[lda1] = l1;
        __syncthreads();

        bf16x8 fAh[4], fAl[4];
        #pragma unroll
        for (int t = 0; t < 4; ++t) {
            int ra = (wr*64 + t*16 + l15) * 32 + qs;
            fAh[t] = *(const bf16x8*)&sAh[ra];
            fAl[t] = *(const bf16x8*)&sAl[ra];
        }
        #pragma unroll
        for (int nt = 0; nt < 4; ++nt) {
            int rb = (wc*64 + nt*16 + l15) * 32 + qs;
            bf16x8 fBh = *(const bf16x8*)&sBh[rb];
            bf16x8 fBl = *(const bf16x8*)&sBl[rb];
            #pragma unroll
            for (int mt = 0; mt < 4; ++mt) {
                acc[mt][nt] = __builtin_amdgcn_mfma_f32_16x16x32_bf16(fAh[mt], fBh, acc[mt][nt], 0, 0, 0);
                acc[mt][nt] = __builtin_amdgcn_mfma_f32_16x16x32_bf16(fAh[mt], fBl, acc[mt][nt], 0, 0, 0);
                acc[mt][nt] = __builtin_amdgcn_mfma_f32_16x16x32_bf16(fAl[mt], fBh, acc[mt][nt], 0, 0, 0);
            }
        }
    }
    if constexpr (OUTMODE == 3) {
        // fused relu + logits: out[n][o] = b2[o] + sum_j relu(h[n][j]+b1[j])*W2[j][o]
        __syncthreads();                       // last fragment reads done
        float* red = (float*)sAh;              // [128 rows][2]
        float pl[16][2];
        #pragma unroll
        for (int mt = 0; mt < 4; ++mt)
            #pragma unroll
            for (int r = 0; r < 4; ++r) {
                float p0 = 0.f, p1 = 0.f;
                #pragma unroll
                for (int nt = 0; nt < 4; ++nt) {
                    int col = wc*64 + nt*16 + l15;
                    float v = fmaxf(acc[mt][nt][r] + bias[col], 0.f);
                    p0 += v * logW2[col*2];
                    p1 += v * logW2[col*2 + 1];
                }
                #pragma unroll
                for (int o = 1; o < 16; o <<= 1) {
                    p0 += __shfl_xor(p0, o);
                    p1 += __shfl_xor(p1, o);
                }
                pl[mt*4 + r][0] = p0;
                pl[mt*4 + r][1] = p1;
            }
        if (wc == 1 && l15 == 0) {
            #pragma unroll
            for (int mt = 0; mt < 4; ++mt)
                #pragma unroll
                for (int r = 0; r < 4; ++r) {
                    int rl = wr*64 + mt*16 + q*4 + r;
                    red[rl*2]     = pl[mt*4 + r][0];
                    red[rl*2 + 1] = pl[mt*4 + r][1];
                }
        }
        __syncthreads();
        if (wc == 0 && l15 == 0) {
            #pragma unroll
            for (int mt = 0; mt < 4; ++mt)
                #pragma unroll
                for (int r = 0; r < 4; ++r) {
                    int rl = wr*64 + mt*16 + q*4 + r;
                    int grow = r0 + rl;
                    if (grow < M) {
                        C[(size_t)grow*2]     = pl[mt*4+r][0] + red[rl*2]     + logB2[0];
                        C[(size_t)grow*2 + 1] = pl[mt*4+r][1] + red[rl*2 + 1] + logB2[1];
                    }
                }
        }
        return;
    }
    if constexpr (OUTMODE == 4) {
        // fused tanh + semantic score: sc[n] = sum_j tanh(t[n][j]+b1[j])*W2[j]
        __syncthreads();
        float* red = (float*)sAh;              // [128 rows]
        float pl[16];
        #pragma unroll
        for (int mt = 0; mt < 4; ++mt)
            #pragma unroll
            for (int r = 0; r < 4; ++r) {
                float pp = 0.f;
                #pragma unroll
                for (int nt = 0; nt < 4; ++nt) {
                    int col = wc*64 + nt*16 + l15;
                    float v = acc[mt][nt][r] + bias[col];
                    float t = __expf(2.f * v);                 // exact tanh
                    v = 1.f - 2.f * fastrcp(1.f + t);
                    pp += v * logW2[col];
                }
                #pragma unroll
                for (int o = 1; o < 16; o <<= 1) pp += __shfl_xor(pp, o);
                pl[mt*4 + r] = pp;
            }
        if (wc == 1 && l15 == 0) {
            #pragma unroll
            for (int mt = 0; mt < 4; ++mt)
                #pragma unroll
                for (int r = 0; r < 4; ++r)
                    red[wr*64 + mt*16 + q*4 + r] = pl[mt*4 + r];
        }
        __syncthreads();
        if (wc == 0 && l15 == 0) {
            #pragma unroll
            for (int mt = 0; mt < 4; ++mt)
                #pragma unroll
                for (int r = 0; r < 4; ++r) {
                    int rl = wr*64 + mt*16 + q*4 + r;
                    int grow = r0 + rl;
                    if (grow < M)
                        C[(size_t)grow*4] = pl[mt*4+r] + red[rl];
                }
        }
        return;
    }
    // epilogue: C/D layout col=lane&15, row=(lane>>4)*4+reg  [m89-verified]
    #pragma unroll
    for (int mt = 0; mt < 4; ++mt)
        #pragma unroll
        for (int nt = 0; nt < 4; ++nt) {
            int col = c0 + wc*64 + nt*16 + l15;
            float bb = bias ? bias[col] : 0.f;
            #pragma unroll
            for (int r = 0; r < 4; ++r) {
                int grow = r0 + wr*64 + mt*16 + q*4 + r;
                if (grow < M) {
                    float v = acc[mt][nt][r] + bb;
                    if (ACT == 1) {
                        float t = __expf(2.f * v);
                        v = 1.f - 2.f * fastrcp(1.f + t);
                    } else if (ACT == 2) v = fmaxf(v, 0.f);
                    size_t o = (size_t)grow * ldc + col;
                    if (OUTMODE == 2) Ch[o] = __float2half(v);
                    else              C[o] = v;
                }
            }
        }
}

// ================= bf16x3 MFMA GEMM, meta-path batched ===================
// FILL=1: blocks bx < G3_FB run fill_edges FIRST (wall starts at t=0).
// Epilogue computes fused attention scores from in-register fp32 acc.
template<int FILL>
__global__ __launch_bounds__(256)
void mfma_gemm3_k(const __half* __restrict__ A16p, int aoffz, int lda,
                  const unsigned short* __restrict__ WT, int l,
                  __half* __restrict__ hp3, int M,
                  const int* __restrict__ edges, int* __restrict__ cnt3,
                  unsigned short* __restrict__ slots3,
                  const float* __restrict__ gatAs, const float* __restrict__ gatAd,
                  float* __restrict__ ssrc3, float* __restrict__ sdst3) {
    __shared__ unsigned short sAh[128*32], sAl[128*32], sBh[128*32], sBl[128*32];
    if constexpr (FILL) {
        if ((int)blockIdx.x < G3_FB) {
            fill_edges(edges, cnt3, slots3,
                       (int)blockIdx.x + G3_FB * ((int)blockIdx.y + 2 * (int)blockIdx.z),
                       PROJ_EB);
            return;
        }
    }
    const int bx0 = FILL ? ((int)blockIdx.x - G3_FB) : (int)blockIdx.x;
    const int p = blockIdx.z;
    const __half* Ap = A16p + (size_t)p * aoffz;
    const unsigned short* WThi = WT + (size_t)(2*p + l) * 131072;
    const unsigned short* WTlo = WThi + 65536;
    __half* Ch = hp3 + (size_t)p * N_NODES * HID;
    const int K = HID;

    const int tid  = threadIdx.x;
    const int lane = tid & 63;
    const int w    = tid >> 6;
    const int wr   = w >> 1, wc = w & 1;
    const int r0   = bx0 * 128;
    const int c0   = blockIdx.y * 128;
    const int l15  = lane & 15, q = lane >> 4;

    const int cl8   = (((lane & 3) ^ ((lane >> 4) & 3)) << 3);
    const int lrow  = w*32 + (lane >> 2);
    const int gbrow0 = c0 + lrow, gbrow1 = c0 + lrow + 16;
    const int lbase = w * 1024;                 // shorts (wave-uniform)

    const int srow = tid >> 2, slot = tid & 3;
    const size_t ga0 = (size_t)min(r0 + srow,      M - 1) * lda + slot * 8;
    const size_t ga1 = (size_t)min(r0 + srow + 64, M - 1) * lda + slot * 8;
    const int lda0 = srow*32 + ((slot ^ ((srow >> 2) & 3)) << 3);
    const int lda1 = lda0 + 64*32;

    f32x4 acc[4][4];
    #pragma unroll
    for (int i = 0; i < 4; ++i)
        #pragma unroll
        for (int j = 0; j < 4; ++j) acc[i][j] = (f32x4){0.f, 0.f, 0.f, 0.f};

    const int swzF = (l15 >> 2) & 3;
    const int qs   = ((q ^ swzF) << 3);

    for (int s = 0; s < 8; ++s) {             // K=256, BK=32
        const int kc = s << 5;
        __syncthreads();
        // B: direct global->LDS, in flight under the A conversion below
        GLL16(&WThi[(size_t)gbrow0*K + kc + cl8], &sBh[lbase]);
        GLL16(&WThi[(size_t)gbrow1*K + kc + cl8], &sBh[lbase + 512]);
        GLL16(&WTlo[(size_t)gbrow0*K + kc + cl8], &sBl[lbase]);
        GLL16(&WTlo[(size_t)gbrow1*K + kc + cl8], &sBl[lbase + 512]);
        uint4 r0v = *(const uint4*)&Ap[ga0 + kc];
        uint4 r1v = *(const uint4*)&Ap[ga1 + kc];
        uint4 h0, l0, h1, l1;
        h8_to_pair(r0v, h0, l0);
        h8_to_pair(r1v, h1, l1);
        *(uint4*)&sAh[lda0] = h0; *(uint4*)&sAl[lda0] = l0;
        *(uint4*)&sAh[lda1] = h1; *(uint4*)&sAl[lda1] = l1;
        __syncthreads();

        bf16x8 fAh[4], fAl[4];
        #pragma unroll
        for (int t = 0; t < 4; ++t) {
            int ra = (wr*64 + t*16 + l15) * 32 + qs;
            fAh[t] = *(const bf16x8*)&sAh[ra];
            fAl[t] = *(const bf16x8*)&sAl[ra];
        }
        #pragma unroll
        for (int nt = 0; nt < 4; ++nt) {
            int rb = (wc*64 + nt*16 + l15) * 32 + qs;
            bf16x8 fBh = *(const bf16x8*)&sBh[rb];
            bf16x8 fBl = *(const bf16x8*)&sBl[rb];
            #pragma unroll
            for (int mt = 0; mt < 4; ++mt) {
                acc[mt][nt] = __builtin_amdgcn_mfma_f32_16x16x32_bf16(fAh[mt], fBh, acc[mt][nt], 0, 0, 0);
                acc[mt][nt] = __builtin_amdgcn_mfma_f32_16x16x32_bf16(fAh[mt], fBl, acc[mt][nt], 0, 0, 0);
                acc[mt][nt] = __builtin_amdgcn_mfma_f32_16x16x32_bf16(fAl[mt], fBh, acc[mt][nt], 0, 0, 0);
            }
        }
    }
    // hp write
    #pragma unroll
    for (int mt = 0; mt < 4; ++mt)
        #pragma unroll
        for (int nt = 0; nt < 4; ++nt) {
            int col = c0 + wc*64 + nt*16 + l15;
            #pragma unroll
            for (int r = 0; r < 4; ++r) {
                int grow = r0 + wr*64 + mt*16 + q*4 + r;
                if (grow < M)
                    Ch[(size_t)grow * HID + col] = __float2half(acc[mt][nt][r]);
            }
        }
    // fused attention scores (heads hb, hb+1 for this wave's 64 cols)
    {
        const float* av = gatAs + (2*p + l) * HID;
        const float* dvv = gatAd + (2*p + l) * HID;
        float as_[4], ad_[4];
        #pragma unroll
        for (int nt = 0; nt < 4; ++nt) {
            int col = c0 + wc*64 + nt*16 + l15;
            as_[nt] = av[col];
            ad_[nt] = dvv[col];
        }
        const int hb = (c0 + wc*64) >> 5;
        #pragma unroll
        for (int mt = 0; mt < 4; ++mt)
            #pragma unroll
            for (int r = 0; r < 4; ++r) {
                float s0 = acc[mt][0][r]*as_[0] + acc[mt][1][r]*as_[1];
                float s1 = acc[mt][2][r]*as_[2] + acc[mt][3][r]*as_[3];
                float d0 = acc[mt][0][r]*ad_[0] + acc[mt][1][r]*ad_[1];
                float d1 = acc[mt][2][r]*ad_[2] + acc[mt][3][r]*ad_[3];
                #pragma unroll
                for (int o = 1; o < 16; o <<= 1) {
                    s0 += __shfl_xor(s0, o); s1 += __shfl_xor(s1, o);
                    d0 += __shfl_xor(d0, o); d1 += __shfl_xor(d1, o);
                }
                if (l15 == 0) {
                    int grow = r0 + wr*64 + mt*16 + q*4 + r;
                    if (grow < M) {
                        size_t ob = (size_t)p * N_NODES * NH + (size_t)grow * NH;
                        ssrc3[ob + hb]     = s0;
                        ssrc3[ob + hb + 1] = s1;
                        sdst3[ob + hb]     = d0;
                        sdst3[ob + hb + 1] = d1;
                    }
                }
            }
    }
}

// ---------------- batched weight transpose+split + cnt3 zero -------------
__global__ __launch_bounds__(256)
void cvtWall_k(const float* __restrict__ gatW, const float* __restrict__ projW,
               const float* __restrict__ semW1, const float* __restrict__ clsW1,
               unsigned short* __restrict__ WT, int* __restrict__ cnt3) {
    int y = blockIdx.y;
    if (y == 9) {          // fold cnt3 zeroing into this dispatch
        for (int i = blockIdx.x * 256 + threadIdx.x; i < 3*N_NODES; i += 256*256)
            cnt3[i] = 0;
        return;
    }
    const float* W; int K, N;
    if (y < 6)       { W = gatW + (size_t)y * 65536; K = 256; N = 256; }
    else if (y == 6) { W = projW; K = 128; N = 256; }
    else if (y == 7) { W = semW1; K = 256; N = 128; }
    else             { W = clsW1; K = 256; N = 128; }
    int idx = blockIdx.x * 256 + threadIdx.x;
    if (idx >= K * N) return;
    unsigned short* hi = WT + (size_t)y * 131072;
    unsigned short* lo = hi + 65536;
    int k = idx / N, n = idx - k * N;
    float v = W[idx];
    unsigned short h = f2bf(v);
    hi[n * K + k] = h;
    lo[n * K + k] = f2bf(v - bf2f(h));
}

// -------------------------------------------------------------------------
extern "C" void kernel_launch(void* const* d_in, const int* in_sizes, int n_in,
                              void* d_out, int out_size, void* d_ws, size_t ws_size,
                              hipStream_t stream) {
    (void)in_sizes; (void)n_in; (void)out_size; (void)ws_size;
    const float* x     = (const float*)d_in[0];
    const int*   edges = (const int*)  d_in[1];
    const float* projW = (const float*)d_in[2];
    const float* projb = (const float*)d_in[3];
    const float* gatW  = (const float*)d_in[4];
    const float* gatAs = (const float*)d_in[5];
    const float* gatAd = (const float*)d_in[6];
    const float* gatB  = (const float*)d_in[7];
    const float* semW1 = (const float*)d_in[8];
    const float* semb1 = (const float*)d_in[9];
    const float* semW2 = (const float*)d_in[10];
    const float* clsW1 = (const float*)d_in[11];
    const float* clsb1 = (const float*)d_in[12];
    const float* clsW2 = (const float*)d_in[13];
    const float* clsb2 = (const float*)d_in[14];
    float* out = (float*)d_out;

    // ---- arena (~216 MB) ----
    char* base = (char*)d_ws;
    const size_t PLANE = (size_t)N_NODES * HID * 2;      // 25.6 MB
    __half* hp3   = (__half*)(base);                      // [3][N,256] fp16
    __half* emb16 = (__half*)(base + 3*PLANE);            // [3][N,256] fp16 (path-major)
    __half* h016  = (__half*)(base + 6*PLANE);            // [N,256] fp16
    char* small = base + 7*PLANE;
    float* ssrc3 = (float*)small;                          // 3*N*8 f32
    float* sdst3 = ssrc3 + 3*(size_t)N_NODES*NH;
    int*   cnt3  = (int*)(sdst3 + 3*(size_t)N_NODES*NH);   // 3*N int
    unsigned short* WT = (unsigned short*)(cnt3 + 3*N_NODES); // 9*131072 shorts
    unsigned short* slots3 = WT + 9*131072;                // 3*N*MAXD ushort
    float* w4 = (float*)(slots3 + (size_t)3*N_NODES*MAXD); // [N][4] f32 (raw scores)

    dim3 blk(256);
    const int gx = (N_NODES + 127) / 128;     // 391

    // weights + cnt3 zero in one dispatch (y=10 planes)
    cvtWall_k<<<dim3(256, 10), blk, 0, stream>>>(gatW, projW, semW1, clsW1, WT, cnt3);

    // proj union: fill edges [0, PROJ_EB) FIRST + h016 = fp16(x@projW+b)
    mfma_gemm_k<256,0,2,0,1><<<dim3(gx + PROJ_FB, 2), blk, 0, stream>>>(
        x, nullptr, 128, WT + 6*131072, WT + 6*131072 + 65536, projb,
        nullptr, h016, 256, N_NODES, 128, edges, cnt3, slots3, nullptr, 0, 0,
        nullptr, nullptr);

    // gemm3 l=0 union: fill edges [PROJ_EB, 3E) FIRST + GEMM (+ attn scores)
    mfma_gemm3_k<1><<<dim3(gx + G3_FB, 2, 3), blk, 0, stream>>>(
        h016, 0, HID, WT, 0, hp3, N_NODES, edges, cnt3, slots3,
        gatAs, gatAd, ssrc3, sdst3);

    // agg l=0, all paths (standalone: 0 LDS, high occupancy)
    agg3y_k<<<dim3(AGGB, 3), blk, 0, stream>>>(
        cnt3, slots3, ssrc3, sdst3, hp3, gatB, 0, emb16);

    // gemm3 l=1 (all paths): reads path-major emb16, writes hp3 + l=1 scores
    mfma_gemm3_k<0><<<dim3(gx, 2, 3), blk, 0, stream>>>(
        emb16, (int)((size_t)N_NODES*HID), HID, WT, 1, hp3, N_NODES,
        nullptr, nullptr, nullptr, gatAs, gatAd, ssrc3, sdst3);

    // agg l=1, all paths
    agg3y_k<<<dim3(AGGB, 3), blk, 0, stream>>>(
        cnt3, slots3, ssrc3, sdst3, hp3, gatB, 1, emb16);

    // semantic GEMMs, 3 paths in ONE dispatch (z = path); OUTMODE=4 fuses
    // tanh + dot(semW2) in the epilogue -> writes raw sc[n*4+p]
    mfma_gemm_k<128,1,4,1,0><<<dim3(gx, 1, 3), blk, 0, stream>>>(
        nullptr, emb16, 256, WT + 7*131072, WT + 7*131072 + 65536, semb1,
        w4, nullptr, 0, N_NODES, 256, nullptr, nullptr, nullptr, nullptr,
        (int)((size_t)N_NODES*HID), 1, semW2, nullptr);

    // classifier: inline softmax(w4 raw scores) -> on-the-fly z, relu +
    // logits fused in epilogue -> writes out[n][2] directly
    mfma_gemm_k<128,2,3,3,0><<<dim3(gx, 1), blk, 0, stream>>>(
        nullptr, emb16, HID, WT + 8*131072, WT + 8*131072 + 65536, clsb1,
        out, nullptr, 0, N_NODES, 256, nullptr, nullptr, nullptr, w4, 0, 0,
        clsW2, clsb2);
}

// Round 17
// 866.317 us; speedup vs baseline: 1.0176x; 1.0176x over previous
//
#include <hip/hip_runtime.h>
#include <hip/hip_fp16.h>
#include <math.h>

#define N_NODES 50000
#define N_EDG   800000
#define NH      8
#define DH      32
#define HID     256
#define MAXD    64    // fixed slots/node; P(in-deg>64 | Poisson(16)) ~ 1e-19
#define EPB     4096  // edges per fill block (256 thr x 16)
#define PROJ_FB 88    // fill blocks per y in proj union (x2 y = 720,896 edges, ~30%)
#define PROJ_EB (176*EPB)
#define G3_FB   69    // fill blocks per (y,z) in gemm3-l0 union (x6, covers rest)
#define AGGB    12500 // agg blocks per path (4 nodes/block)

typedef __attribute__((ext_vector_type(8))) short bf16x8;
typedef __attribute__((ext_vector_type(4))) float f32x4;

// direct global->LDS, 16B/lane: dst must be wave-uniform base (HW adds
// lane*16B); source address is per-lane (carries the swizzle).
#define GLL16(src, dst) __builtin_amdgcn_global_load_lds(                  \
    (const __attribute__((address_space(1))) void*)(const void*)(src),     \
    (__attribute__((address_space(3))) void*)(dst), 16, 0, 0)

__device__ __forceinline__ unsigned short f2bf(float x) {
    unsigned u = __float_as_uint(x);
    u += 0x7FFF + ((u >> 16) & 1);          // RNE
    return (unsigned short)(u >> 16);
}
__device__ __forceinline__ float bf2f(unsigned short h) {
    return __uint_as_float(((unsigned)h) << 16);
}
// packed f32 pair -> 2x bf16 (RNE, bit-identical to f2bf; inline asm)
__device__ __forceinline__ unsigned cvtpk_bf16(float a, float b) {
    unsigned r;
    asm("v_cvt_pk_bf16_f32 %0, %1, %2" : "=v"(r) : "v"(a), "v"(b));
    return r;
}
__device__ __forceinline__ float fastrcp(float x) {
    float r;
    asm("v_rcp_f32 %0, %1" : "=v"(r) : "v"(x));
    return r;
}
// 8 f32 -> bf16 hi/lo planes, cvt_pk based
__device__ __forceinline__ void split8(const float4& a, const float4& b,
                                       uint4& hi, uint4& lo) {
    float f[8] = {a.x,a.y,a.z,a.w,b.x,b.y,b.z,b.w};
    unsigned hpk[4], lpk[4];
    #pragma unroll
    for (int i = 0; i < 4; ++i) {
        hpk[i] = cvtpk_bf16(f[2*i], f[2*i+1]);
        float hl = __uint_as_float(hpk[i] << 16);           // bf2f(lo half)
        float hh = __uint_as_float(hpk[i] & 0xffff0000u);   // bf2f(hi half)
        lpk[i] = cvtpk_bf16(f[2*i] - hl, f[2*i+1] - hh);
    }
    hi = make_uint4(hpk[0], hpk[1], hpk[2], hpk[3]);
    lo = make_uint4(lpk[0], lpk[1], lpk[2], lpk[3]);
}
// 8 fp16 -> bf16 hi/lo planes (EXACT split)
__device__ __forceinline__ void h8_to_pair(uint4 r, uint4& hi, uint4& lo) {
    const __half2* hp = (const __half2*)&r;
    unsigned hpk[4], lpk[4];
    #pragma unroll
    for (int i = 0; i < 4; ++i) {
        float2 f = __half22float2(hp[i]);
        hpk[i] = cvtpk_bf16(f.x, f.y);
        float hl = __uint_as_float(hpk[i] << 16);
        float hh = __uint_as_float(hpk[i] & 0xffff0000u);
        lpk[i] = cvtpk_bf16(f.x - hl, f.y - hh);
    }
    hi = make_uint4(hpk[0], hpk[1], hpk[2], hpk[3]);
    lo = make_uint4(lpk[0], lpk[1], lpk[2], lpk[3]);
}

// fused f16->f32 convert + FMA (bit-identical to cvt+fma, 1 VALU op)
__device__ __forceinline__ void fmix2(float& alo, float& ahi, unsigned rv, float w) {
    asm("v_fma_mix_f32 %0, %1, %2, %0 op_sel:[0,0,0] op_sel_hi:[1,0,0]"
        : "+v"(alo) : "v"(rv), "v"(w));
    asm("v_fma_mix_f32 %0, %1, %2, %0 op_sel:[1,0,0] op_sel_hi:[1,0,0]"
        : "+v"(ahi) : "v"(rv), "v"(w));
}

// ---- adjacency-build worker (far-end throughput-bound; rides GEMMs.
// Fill blocks at LOW blockIdx.x so the wall starts at t=0. R16 falsified
// the 51/49 split: overlap quality scales with co-resident GEMM duration,
// so most fill belongs with the LONG GEMM (l0 union) -> 30/70 restored.)
__device__ __forceinline__ void fill_edges(const int* __restrict__ edges,
                                           int* __restrict__ cnt3,
                                           unsigned short* __restrict__ slots3,
                                           int fb, int ebase) {
    const int base = ebase + fb * EPB + (int)threadIdx.x;
    #pragma unroll 1
    for (int t = 0; t < 4; ++t) {
        int dd[4], ss[4];
        #pragma unroll
        for (int j = 0; j < 4; ++j) {
            int e = base + (t * 4 + j) * 256;
            if (e < 3 * N_EDG) {
                int p = e / N_EDG, i = e - p * N_EDG;
                const int* src = edges + (size_t)p * 2 * N_EDG;
                int s = src[i], d = src[N_EDG + i];
                ss[j] = min(max(s, 0), N_NODES - 1);
                dd[j] = p * N_NODES + min(max(d, 0), N_NODES - 1);
            } else { ss[j] = -1; dd[j] = 0; }
        }
        int pos[4];
        #pragma unroll
        for (int j = 0; j < 4; ++j)
            if (ss[j] >= 0) pos[j] = atomicAdd(&cnt3[dd[j]], 1);
        #pragma unroll
        for (int j = 0; j < 4; ++j)
            if (ss[j] >= 0 && pos[j] < MAXD)
                slots3[(size_t)dd[j] * MAXD + pos[j]] = (unsigned short)ss[j];
    }
}

// ---- segment-softmax aggregation worker (R6 form; fabric-bound ~4 TB/s).
__device__ __forceinline__ void agg_worker(
    int fb, int p, int l,
    const int* __restrict__ cnt3, const unsigned short* __restrict__ slots3,
    const float* __restrict__ ssrc3, const float* __restrict__ sdst3,
    const __half* __restrict__ hp3, const float* __restrict__ gatB,
    __half* __restrict__ emb16) {
    const int wid  = fb * 4 + ((int)threadIdx.x >> 6);
    const int lane = threadIdx.x & 63;
    if (wid >= N_NODES) return;
    const int n = wid;
    const unsigned short* srcs = slots3 + ((size_t)p * N_NODES + n) * MAXD;
    const float* s_src = ssrc3 + p * N_NODES * NH;
    const float* s_dst = sdst3 + p * N_NODES * NH;
    const __half* hp = hp3 + (size_t)p * N_NODES * HID;
    const float* bias = gatB + (2*p + l) * HID;
    const int deg = min(cnt3[p * N_NODES + n], MAXD);

    const int sub = lane & 31, eo = lane >> 5;
    const int h2  = sub >> 2;
    const float sd2 = s_dst[n*NH + h2];
    const uint4* hp4 = (const uint4*)hp;
    float dn = 0.f;
    float a0=0.f,a1=0.f,a2=0.f,a3=0.f,a4=0.f,a5=0.f,a6=0.f,a7=0.f;

    int i = eo;
    for (; i + 6 < deg; i += 8) {
        const int s0 = srcs[i];
        const int s1 = srcs[i + 2];
        const int s2 = srcs[i + 4];
        const int s3 = srcs[i + 6];
        const float x0 = s_src[s0*NH + h2];
        const float x1 = s_src[s1*NH + h2];
        const float x2 = s_src[s2*NH + h2];
        const float x3 = s_src[s3*NH + h2];
        const uint4 r0 = hp4[s0*32 + sub];
        const uint4 r1 = hp4[s1*32 + sub];
        const uint4 r2 = hp4[s2*32 + sub];
        const uint4 r3 = hp4[s3*32 + sub];
        float e0 = x0 + sd2; e0 = e0 > 0.f ? e0 : 0.2f * e0;
        float e1 = x1 + sd2; e1 = e1 > 0.f ? e1 : 0.2f * e1;
        float e2 = x2 + sd2; e2 = e2 > 0.f ? e2 : 0.2f * e2;
        float e3 = x3 + sd2; e3 = e3 > 0.f ? e3 : 0.2f * e3;
        const float w0 = __expf(e0), w1 = __expf(e1);
        const float w2 = __expf(e2), w3 = __expf(e3);
        dn += w0; dn += w1; dn += w2; dn += w3;
        fmix2(a0, a1, r0.x, w0); fmix2(a2, a3, r0.y, w0);
        fmix2(a4, a5, r0.z, w0); fmix2(a6, a7, r0.w, w0);
        fmix2(a0, a1, r1.x, w1); fmix2(a2, a3, r1.y, w1);
        fmix2(a4, a5, r1.z, w1); fmix2(a6, a7, r1.w, w1);
        fmix2(a0, a1, r2.x, w2); fmix2(a2, a3, r2.y, w2);
        fmix2(a4, a5, r2.z, w2); fmix2(a6, a7, r2.w, w2);
        fmix2(a0, a1, r3.x, w3); fmix2(a2, a3, r3.y, w3);
        fmix2(a4, a5, r3.z, w3); fmix2(a6, a7, r3.w, w3);
    }
    for (; i + 2 < deg; i += 4) {
        const int s0 = srcs[i];
        const int s1 = srcs[i + 2];
        const float x0 = s_src[s0*NH + h2];
        const float x1 = s_src[s1*NH + h2];
        const uint4 r0 = hp4[s0*32 + sub];
        const uint4 r1 = hp4[s1*32 + sub];
        float e0 = x0 + sd2; e0 = e0 > 0.f ? e0 : 0.2f * e0;
        float e1 = x1 + sd2; e1 = e1 > 0.f ? e1 : 0.2f * e1;
        const float w0 = __expf(e0), w1 = __expf(e1);
        dn += w0; dn += w1;
        fmix2(a0, a1, r0.x, w0); fmix2(a2, a3, r0.y, w0);
        fmix2(a4, a5, r0.z, w0); fmix2(a6, a7, r0.w, w0);
        fmix2(a0, a1, r1.x, w1); fmix2(a2, a3, r1.y, w1);
        fmix2(a4, a5, r1.z, w1); fmix2(a6, a7, r1.w, w1);
    }
    if (i < deg) {
        const int s0 = srcs[i];
        const float x0 = s_src[s0*NH + h2];
        const uint4 r0 = hp4[s0*32 + sub];
        float e0 = x0 + sd2; e0 = e0 > 0.f ? e0 : 0.2f * e0;
        const float w0 = __expf(e0);
        dn += w0;
        fmix2(a0, a1, r0.x, w0); fmix2(a2, a3, r0.y, w0);
        fmix2(a4, a5, r0.z, w0); fmix2(a6, a7, r0.w, w0);
    }
    dn += __shfl_xor(dn, 32);
    a0 += __shfl_xor(a0, 32); a1 += __shfl_xor(a1, 32);
    a2 += __shfl_xor(a2, 32); a3 += __shfl_xor(a3, 32);
    a4 += __shfl_xor(a4, 32); a5 += __shfl_xor(a5, 32);
    a6 += __shfl_xor(a6, 32); a7 += __shfl_xor(a7, 32);
    if (lane < 32) {
        float evs = s_src[n*NH + h2] + sd2;
        evs = evs > 0.f ? evs : 0.2f * evs;
        float ws = __expf(evs);
        dn += ws;
        const uint4 rs = hp4[n*32 + sub];
        fmix2(a0, a1, rs.x, ws); fmix2(a2, a3, rs.y, ws);
        fmix2(a4, a5, rs.z, ws); fmix2(a6, a7, rs.w, ws);

        float rdn = fastrcp(dn);
        float v[8] = {a0,a1,a2,a3,a4,a5,a6,a7};
        const float4 b0 = *(const float4*)&bias[sub*8];
        const float4 b1 = *(const float4*)&bias[sub*8 + 4];
        v[0]=v[0]*rdn+b0.x; v[1]=v[1]*rdn+b0.y; v[2]=v[2]*rdn+b0.z; v[3]=v[3]*rdn+b0.w;
        v[4]=v[4]*rdn+b1.x; v[5]=v[5]*rdn+b1.y; v[6]=v[6]*rdn+b1.z; v[7]=v[7]*rdn+b1.w;
        unsigned short hh[8];
        #pragma unroll
        for (int k = 0; k < 8; ++k) {
            float e = v[k] > 0.f ? v[k] : (__expf(v[k]) - 1.f);   // ELU
            hh[k] = __half_as_ushort(__float2half(e));
        }
        size_t o = ((size_t)p * N_NODES + n) * HID + sub * 8;   // path-major
        *(uint4*)&emb16[o] = make_uint4(hh[0]|((unsigned)hh[1]<<16), hh[2]|((unsigned)hh[3]<<16),
                                        hh[4]|((unsigned)hh[5]<<16), hh[6]|((unsigned)hh[7]<<16));
    }
}

// standalone agg: grid (AGGB, 3), blockIdx.y = path. 0 LDS -> 78% occupancy.
__global__ __launch_bounds__(256)
void agg3y_k(const int* __restrict__ cnt3, const unsigned short* __restrict__ slots3,
             const float* __restrict__ ssrc3, const float* __restrict__ sdst3,
             const __half* __restrict__ hp3, const float* __restrict__ gatB,
             int l, __half* __restrict__ emb16) {
    agg_worker(blockIdx.x, blockIdx.y, l, cnt3, slots3, ssrc3, sdst3, hp3, gatB, emb16);
}

// ================= bf16x3 MFMA GEMM, single =============================
// FILL=1: blocks bx < PROJ_FB run fill_edges FIRST (wall starts at t=0).
// AMODE: 0 f32 A, 1 fp16 A, 3 on-the-fly z with INLINE softmax of raw
//        semantic scores (w4z holds raw sc[n*4+p]).
// OUTMODE: 0 f32, 2 fp16, 3 fused relu+logits (out[n][2]),
//          4 fused tanh+semscore dot (writes sc[n*4+z]).
template<int NC, int ACT, int OUTMODE, int AMODE, int FILL>
__global__ __launch_bounds__(256)
void mfma_gemm_k(const float* __restrict__ A32p, const __half* __restrict__ A16p,
                 int lda,
                 const unsigned short* __restrict__ WThi,
                 const unsigned short* __restrict__ WTlo,
                 const float* __restrict__ bias,
                 float* __restrict__ C, __half* __restrict__ Ch,
                 int ldc, int M, int K,
                 const int* __restrict__ edges, int* __restrict__ cnt3,
                 unsigned short* __restrict__ slots3,
                 const float* __restrict__ w4z,
                 int aplanez, int cplanez,
                 const float* __restrict__ logW2, const float* __restrict__ logB2) {
    __shared__ unsigned short sAh[128*32], sAl[128*32], sBh[128*32], sBl[128*32];
    if constexpr (FILL) {
        if ((int)blockIdx.x < PROJ_FB) {
            fill_edges(edges, cnt3, slots3,
                       (int)blockIdx.x + PROJ_FB * (int)blockIdx.y, 0);
            return;
        }
    }
    const int bx0 = FILL ? ((int)blockIdx.x - PROJ_FB) : (int)blockIdx.x;
    if (A16p) A16p += (size_t)blockIdx.z * aplanez;
    if (C)    C    += (size_t)blockIdx.z * cplanez;
    const int tid  = threadIdx.x;
    const int lane = tid & 63;
    const int w    = tid >> 6;
    const int wr   = w >> 1, wc = w & 1;
    const int r0   = bx0 * 128;
    const int c0   = blockIdx.y * 128;
    const int l15  = lane & 15, q = lane >> 4;

    const int cl8   = (((lane & 3) ^ ((lane >> 4) & 3)) << 3);
    const int lrow  = w*32 + (lane >> 2);
    const int gbrow0 = c0 + lrow, gbrow1 = c0 + lrow + 16;
    const int lbase = w * 1024;                 // shorts (wave-uniform)

    const int srow = tid >> 2, slot = tid & 3;
    const int arow0 = min(r0 + srow,      M - 1);
    const int arow1 = min(r0 + srow + 64, M - 1);
    const size_t ga0 = (size_t)arow0 * lda + slot * 8;
    const size_t ga1 = (size_t)arow1 * lda + slot * 8;
    const int lda0 = srow*32 + ((slot ^ ((srow >> 2) & 3)) << 3);
    const int lda1 = lda0 + 64*32;

    float4 w0r, w1r;
    if constexpr (AMODE == 3) {
        // raw scores -> inline 3-way softmax
        float4 s0v = *(const float4*)&w4z[arow0 * 4];
        float4 s1v = *(const float4*)&w4z[arow1 * 4];
        float m0 = fmaxf(s0v.x, fmaxf(s0v.y, s0v.z));
        float m1 = fmaxf(s1v.x, fmaxf(s1v.y, s1v.z));
        float e00 = __expf(s0v.x-m0), e01 = __expf(s0v.y-m0), e02 = __expf(s0v.z-m0);
        float e10 = __expf(s1v.x-m1), e11 = __expf(s1v.y-m1), e12 = __expf(s1v.z-m1);
        float r0s = fastrcp(e00+e01+e02), r1s = fastrcp(e10+e11+e12);
        w0r = make_float4(e00*r0s, e01*r0s, e02*r0s, 0.f);
        w1r = make_float4(e10*r1s, e11*r1s, e12*r1s, 0.f);
    }

    f32x4 acc[4][4];
    #pragma unroll
    for (int i = 0; i < 4; ++i)
        #pragma unroll
        for (int j = 0; j < 4; ++j) acc[i][j] = (f32x4){0.f, 0.f, 0.f, 0.f};

    const int swzF = (l15 >> 2) & 3;
    const int qs   = ((q ^ swzF) << 3);

    const int nsteps = K >> 5;
    for (int s = 0; s < nsteps; ++s) {
        const int kc = s << 5;
        __syncthreads();
        // B: direct global->LDS, in flight under the A conversion below
        GLL16(&WThi[(size_t)gbrow0*K + kc + cl8], &sBh[lbase]);
        GLL16(&WThi[(size_t)gbrow1*K + kc + cl8], &sBh[lbase + 512]);
        GLL16(&WTlo[(size_t)gbrow0*K + kc + cl8], &sBl[lbase]);
        GLL16(&WTlo[(size_t)gbrow1*K + kc + cl8], &sBl[lbase + 512]);
        uint4 h0, l0, h1, l1;
        if constexpr (AMODE == 0) {
            float4 f0a = *(const float4*)&A32p[ga0 + kc];
            float4 f0b = *(const float4*)&A32p[ga0 + kc + 4];
            float4 f1a = *(const float4*)&A32p[ga1 + kc];
            float4 f1b = *(const float4*)&A32p[ga1 + kc + 4];
            split8(f0a, f0b, h0, l0);
            split8(f1a, f1b, h1, l1);
        } else if constexpr (AMODE == 1) {
            uint4 r0v = *(const uint4*)&A16p[ga0 + kc];
            uint4 r1v = *(const uint4*)&A16p[ga1 + kc];
            h8_to_pair(r0v, h0, l0);
            h8_to_pair(r1v, h1, l1);
        } else {   // AMODE == 3
            const int off = kc + slot * 8;
            #pragma unroll
            for (int rr = 0; rr < 2; ++rr) {
                const int row = rr ? arow1 : arow0;
                const float4 wv = rr ? w1r : w0r;
                const __half2* e0 = (const __half2*)&A16p[(size_t)row * HID + off];
                const __half2* e1 = (const __half2*)&A16p[((size_t)N_NODES + row) * HID + off];
                const __half2* e2 = (const __half2*)&A16p[((size_t)2*N_NODES + row) * HID + off];
                float vv[8];
                #pragma unroll
                for (int j2 = 0; j2 < 4; ++j2) {
                    float2 fa = __half22float2(e0[j2]);
                    float2 fb2 = __half22float2(e1[j2]);
                    float2 fc = __half22float2(e2[j2]);
                    vv[2*j2]   = wv.x*fa.x + wv.y*fb2.x + wv.z*fc.x;
                    vv[2*j2+1] = wv.x*fa.y + wv.y*fb2.y + wv.z*fc.y;
                }
                if (rr) split8(*(const float4*)&vv[0], *(const float4*)&vv[4], h1, l1);
                else    split8(*(const float4*)&vv[0], *(const float4*)&vv[4], h0, l0);
            }
        }
        *(uint4*)&sAh[lda0] = h0; *(uint4*)&sAl[lda0] = l0;
        *(uint4*)&sAh[lda1] = h1; *(uint4*)&sAl[lda1] = l1;
        __syncthreads();

        bf16x8 fAh[4], fAl[4];
        #pragma unroll
        for (int t = 0; t < 4; ++t) {
            int ra = (wr*64 + t*16 + l15) * 32 + qs;
            fAh[t] = *(const bf16x8*)&sAh[ra];
            fAl[t] = *(const bf16x8*)&sAl[ra];
        }
        #pragma unroll
        for (int nt = 0; nt < 4; ++nt) {
            int rb = (wc*64 + nt*16 + l15) * 32 + qs;
            bf16x8 fBh = *(const bf16x8*)&sBh[rb];
            bf16x8 fBl = *(const bf16x8*)&sBl[rb];
            #pragma unroll
            for (int mt = 0; mt < 4; ++mt) {
                acc[mt][nt] = __builtin_amdgcn_mfma_f32_16x16x32_bf16(fAh[mt], fBh, acc[mt][nt], 0, 0, 0);
                acc[mt][nt] = __builtin_amdgcn_mfma_f32_16x16x32_bf16(fAh[mt], fBl, acc[mt][nt], 0, 0, 0);
                acc[mt][nt] = __builtin_amdgcn_mfma_f32_16x16x32_bf16(fAl[mt], fBh, acc[mt][nt], 0, 0, 0);
            }
        }
    }
    if constexpr (OUTMODE == 3) {
        // fused relu + logits: out[n][o] = b2[o] + sum_j relu(h[n][j]+b1[j])*W2[j][o]
        __syncthreads();                       // last fragment reads done
        float* red = (float*)sAh;              // [128 rows][2]
        float pl[16][2];
        #pragma unroll
        for (int mt = 0; mt < 4; ++mt)
            #pragma unroll
            for (int r = 0; r < 4; ++r) {
                float p0 = 0.f, p1 = 0.f;
                #pragma unroll
                for (int nt = 0; nt < 4; ++nt) {
                    int col = wc*64 + nt*16 + l15;
                    float v = fmaxf(acc[mt][nt][r] + bias[col], 0.f);
                    p0 += v * logW2[col*2];
                    p1 += v * logW2[col*2 + 1];
                }
                #pragma unroll
                for (int o = 1; o < 16; o <<= 1) {
                    p0 += __shfl_xor(p0, o);
                    p1 += __shfl_xor(p1, o);
                }
                pl[mt*4 + r][0] = p0;
                pl[mt*4 + r][1] = p1;
            }
        if (wc == 1 && l15 == 0) {
            #pragma unroll
            for (int mt = 0; mt < 4; ++mt)
                #pragma unroll
                for (int r = 0; r < 4; ++r) {
                    int rl = wr*64 + mt*16 + q*4 + r;
                    red[rl*2]     = pl[mt*4 + r][0];
                    red[rl*2 + 1] = pl[mt*4 + r][1];
                }
        }
        __syncthreads();
        if (wc == 0 && l15 == 0) {
            #pragma unroll
            for (int mt = 0; mt < 4; ++mt)
                #pragma unroll
                for (int r = 0; r < 4; ++r) {
                    int rl = wr*64 + mt*16 + q*4 + r;
                    int grow = r0 + rl;
                    if (grow < M) {
                        C[(size_t)grow*2]     = pl[mt*4+r][0] + red[rl*2]     + logB2[0];
                        C[(size_t)grow*2 + 1] = pl[mt*4+r][1] + red[rl*2 + 1] + logB2[1];
                    }
                }
        }
        return;
    }
    if constexpr (OUTMODE == 4) {
        // fused tanh + semantic score: sc[n] = sum_j tanh(t[n][j]+b1[j])*W2[j]
        __syncthreads();
        float* red = (float*)sAh;              // [128 rows]
        float pl[16];
        #pragma unroll
        for (int mt = 0; mt < 4; ++mt)
            #pragma unroll
            for (int r = 0; r < 4; ++r) {
                float pp = 0.f;
                #pragma unroll
                for (int nt = 0; nt < 4; ++nt) {
                    int col = wc*64 + nt*16 + l15;
                    float v = acc[mt][nt][r] + bias[col];
                    float t = __expf(2.f * v);                 // exact tanh
                    v = 1.f - 2.f * fastrcp(1.f + t);
                    pp += v * logW2[col];
                }
                #pragma unroll
                for (int o = 1; o < 16; o <<= 1) pp += __shfl_xor(pp, o);
                pl[mt*4 + r] = pp;
            }
        if (wc == 1 && l15 == 0) {
            #pragma unroll
            for (int mt = 0; mt < 4; ++mt)
                #pragma unroll
                for (int r = 0; r < 4; ++r)
                    red[wr*64 + mt*16 + q*4 + r] = pl[mt*4 + r];
        }
        __syncthreads();
        if (wc == 0 && l15 == 0) {
            #pragma unroll
            for (int mt = 0; mt < 4; ++mt)
                #pragma unroll
                for (int r = 0; r < 4; ++r) {
                    int rl = wr*64 + mt*16 + q*4 + r;
                    int grow = r0 + rl;
                    if (grow < M)
                        C[(size_t)grow*4] = pl[mt*4+r] + red[rl];
                }
        }
        return;
    }
    // epilogue: C/D layout col=lane&15, row=(lane>>4)*4+reg  [m89-verified]
    #pragma unroll
    for (int mt = 0; mt < 4; ++mt)
        #pragma unroll
        for (int nt = 0; nt < 4; ++nt) {
            int col = c0 + wc*64 + nt*16 + l15;
            float bb = bias ? bias[col] : 0.f;
            #pragma unroll
            for (int r = 0; r < 4; ++r) {
                int grow = r0 + wr*64 + mt*16 + q*4 + r;
                if (grow < M) {
                    float v = acc[mt][nt][r] + bb;
                    if (ACT == 1) {
                        float t = __expf(2.f * v);
                        v = 1.f - 2.f * fastrcp(1.f + t);
                    } else if (ACT == 2) v = fmaxf(v, 0.f);
                    size_t o = (size_t)grow * ldc + col;
                    if (OUTMODE == 2) Ch[o] = __float2half(v);
                    else              C[o] = v;
                }
            }
        }
}

// ================= bf16x3 MFMA GEMM, meta-path batched ===================
// FILL=1: blocks bx < G3_FB run fill_edges FIRST (wall starts at t=0).
// Epilogue computes fused attention scores from in-register fp32 acc.
template<int FILL>
__global__ __launch_bounds__(256)
void mfma_gemm3_k(const __half* __restrict__ A16p, int aoffz, int lda,
                  const unsigned short* __restrict__ WT, int l,
                  __half* __restrict__ hp3, int M,
                  const int* __restrict__ edges, int* __restrict__ cnt3,
                  unsigned short* __restrict__ slots3,
                  const float* __restrict__ gatAs, const float* __restrict__ gatAd,
                  float* __restrict__ ssrc3, float* __restrict__ sdst3) {
    __shared__ unsigned short sAh[128*32], sAl[128*32], sBh[128*32], sBl[128*32];
    if constexpr (FILL) {
        if ((int)blockIdx.x < G3_FB) {
            fill_edges(edges, cnt3, slots3,
                       (int)blockIdx.x + G3_FB * ((int)blockIdx.y + 2 * (int)blockIdx.z),
                       PROJ_EB);
            return;
        }
    }
    const int bx0 = FILL ? ((int)blockIdx.x - G3_FB) : (int)blockIdx.x;
    const int p = blockIdx.z;
    const __half* Ap = A16p + (size_t)p * aoffz;
    const unsigned short* WThi = WT + (size_t)(2*p + l) * 131072;
    const unsigned short* WTlo = WThi + 65536;
    __half* Ch = hp3 + (size_t)p * N_NODES * HID;
    const int K = HID;

    const int tid  = threadIdx.x;
    const int lane = tid & 63;
    const int w    = tid >> 6;
    const int wr   = w >> 1, wc = w & 1;
    const int r0   = bx0 * 128;
    const int c0   = blockIdx.y * 128;
    const int l15  = lane & 15, q = lane >> 4;

    const int cl8   = (((lane & 3) ^ ((lane >> 4) & 3)) << 3);
    const int lrow  = w*32 + (lane >> 2);
    const int gbrow0 = c0 + lrow, gbrow1 = c0 + lrow + 16;
    const int lbase = w * 1024;                 // shorts (wave-uniform)

    const int srow = tid >> 2, slot = tid & 3;
    const size_t ga0 = (size_t)min(r0 + srow,      M - 1) * lda + slot * 8;
    const size_t ga1 = (size_t)min(r0 + srow + 64, M - 1) * lda + slot * 8;
    const int lda0 = srow*32 + ((slot ^ ((srow >> 2) & 3)) << 3);
    const int lda1 = lda0 + 64*32;

    f32x4 acc[4][4];
    #pragma unroll
    for (int i = 0; i < 4; ++i)
        #pragma unroll
        for (int j = 0; j < 4; ++j) acc[i][j] = (f32x4){0.f, 0.f, 0.f, 0.f};

    const int swzF = (l15 >> 2) & 3;
    const int qs   = ((q ^ swzF) << 3);

    for (int s = 0; s < 8; ++s) {             // K=256, BK=32
        const int kc = s << 5;
        __syncthreads();
        // B: direct global->LDS, in flight under the A conversion below
        GLL16(&WThi[(size_t)gbrow0*K + kc + cl8], &sBh[lbase]);
        GLL16(&WThi[(size_t)gbrow1*K + kc + cl8], &sBh[lbase + 512]);
        GLL16(&WTlo[(size_t)gbrow0*K + kc + cl8], &sBl[lbase]);
        GLL16(&WTlo[(size_t)gbrow1*K + kc + cl8], &sBl[lbase + 512]);
        uint4 r0v = *(const uint4*)&Ap[ga0 + kc];
        uint4 r1v = *(const uint4*)&Ap[ga1 + kc];
        uint4 h0, l0, h1, l1;
        h8_to_pair(r0v, h0, l0);
        h8_to_pair(r1v, h1, l1);
        *(uint4*)&sAh[lda0] = h0; *(uint4*)&sAl[lda0] = l0;
        *(uint4*)&sAh[lda1] = h1; *(uint4*)&sAl[lda1] = l1;
        __syncthreads();

        bf16x8 fAh[4], fAl[4];
        #pragma unroll
        for (int t = 0; t < 4; ++t) {
            int ra = (wr*64 + t*16 + l15) * 32 + qs;
            fAh[t] = *(const bf16x8*)&sAh[ra];
            fAl[t] = *(const bf16x8*)&sAl[ra];
        }
        #pragma unroll
        for (int nt = 0; nt < 4; ++nt) {
            int rb = (wc*64 + nt*16 + l15) * 32 + qs;
            bf16x8 fBh = *(const bf16x8*)&sBh[rb];
            bf16x8 fBl = *(const bf16x8*)&sBl[rb];
            #pragma unroll
            for (int mt = 0; mt < 4; ++mt) {
                acc[mt][nt] = __builtin_amdgcn_mfma_f32_16x16x32_bf16(fAh[mt], fBh, acc[mt][nt], 0, 0, 0);
                acc[mt][nt] = __builtin_amdgcn_mfma_f32_16x16x32_bf16(fAh[mt], fBl, acc[mt][nt], 0, 0, 0);
                acc[mt][nt] = __builtin_amdgcn_mfma_f32_16x16x32_bf16(fAl[mt], fBh, acc[mt][nt], 0, 0, 0);
            }
        }
    }
    // hp write
    #pragma unroll
    for (int mt = 0; mt < 4; ++mt)
        #pragma unroll
        for (int nt = 0; nt < 4; ++nt) {
            int col = c0 + wc*64 + nt*16 + l15;
            #pragma unroll
            for (int r = 0; r < 4; ++r) {
                int grow = r0 + wr*64 + mt*16 + q*4 + r;
                if (grow < M)
                    Ch[(size_t)grow * HID + col] = __float2half(acc[mt][nt][r]);
            }
        }
    // fused attention scores (heads hb, hb+1 for this wave's 64 cols)
    {
        const float* av = gatAs + (2*p + l) * HID;
        const float* dvv = gatAd + (2*p + l) * HID;
        float as_[4], ad_[4];
        #pragma unroll
        for (int nt = 0; nt < 4; ++nt) {
            int col = c0 + wc*64 + nt*16 + l15;
            as_[nt] = av[col];
            ad_[nt] = dvv[col];
        }
        const int hb = (c0 + wc*64) >> 5;
        #pragma unroll
        for (int mt = 0; mt < 4; ++mt)
            #pragma unroll
            for (int r = 0; r < 4; ++r) {
                float s0 = acc[mt][0][r]*as_[0] + acc[mt][1][r]*as_[1];
                float s1 = acc[mt][2][r]*as_[2] + acc[mt][3][r]*as_[3];
                float d0 = acc[mt][0][r]*ad_[0] + acc[mt][1][r]*ad_[1];
                float d1 = acc[mt][2][r]*ad_[2] + acc[mt][3][r]*ad_[3];
                #pragma unroll
                for (int o = 1; o < 16; o <<= 1) {
                    s0 += __shfl_xor(s0, o); s1 += __shfl_xor(s1, o);
                    d0 += __shfl_xor(d0, o); d1 += __shfl_xor(d1, o);
                }
                if (l15 == 0) {
                    int grow = r0 + wr*64 + mt*16 + q*4 + r;
                    if (grow < M) {
                        size_t ob = (size_t)p * N_NODES * NH + (size_t)grow * NH;
                        ssrc3[ob + hb]     = s0;
                        ssrc3[ob + hb + 1] = s1;
                        sdst3[ob + hb]     = d0;
                        sdst3[ob + hb + 1] = d1;
                    }
                }
            }
    }
}

// ---------------- batched weight transpose+split + cnt3 zero -------------
__global__ __launch_bounds__(256)
void cvtWall_k(const float* __restrict__ gatW, const float* __restrict__ projW,
               const float* __restrict__ semW1, const float* __restrict__ clsW1,
               unsigned short* __restrict__ WT, int* __restrict__ cnt3) {
    int y = blockIdx.y;
    if (y == 9) {          // fold cnt3 zeroing into this dispatch
        for (int i = blockIdx.x * 256 + threadIdx.x; i < 3*N_NODES; i += 256*256)
            cnt3[i] = 0;
        return;
    }
    const float* W; int K, N;
    if (y < 6)       { W = gatW + (size_t)y * 65536; K = 256; N = 256; }
    else if (y == 6) { W = projW; K = 128; N = 256; }
    else if (y == 7) { W = semW1; K = 256; N = 128; }
    else             { W = clsW1; K = 256; N = 128; }
    int idx = blockIdx.x * 256 + threadIdx.x;
    if (idx >= K * N) return;
    unsigned short* hi = WT + (size_t)y * 131072;
    unsigned short* lo = hi + 65536;
    int k = idx / N, n = idx - k * N;
    float v = W[idx];
    unsigned short h = f2bf(v);
    hi[n * K + k] = h;
    lo[n * K + k] = f2bf(v - bf2f(h));
}

// -------------------------------------------------------------------------
extern "C" void kernel_launch(void* const* d_in, const int* in_sizes, int n_in,
                              void* d_out, int out_size, void* d_ws, size_t ws_size,
                              hipStream_t stream) {
    (void)in_sizes; (void)n_in; (void)out_size; (void)ws_size;
    const float* x     = (const float*)d_in[0];
    const int*   edges = (const int*)  d_in[1];
    const float* projW = (const float*)d_in[2];
    const float* projb = (const float*)d_in[3];
    const float* gatW  = (const float*)d_in[4];
    const float* gatAs = (const float*)d_in[5];
    const float* gatAd = (const float*)d_in[6];
    const float* gatB  = (const float*)d_in[7];
    const float* semW1 = (const float*)d_in[8];
    const float* semb1 = (const float*)d_in[9];
    const float* semW2 = (const float*)d_in[10];
    const float* clsW1 = (const float*)d_in[11];
    const float* clsb1 = (const float*)d_in[12];
    const float* clsW2 = (const float*)d_in[13];
    const float* clsb2 = (const float*)d_in[14];
    float* out = (float*)d_out;

    // ---- arena (~216 MB) ----
    char* base = (char*)d_ws;
    const size_t PLANE = (size_t)N_NODES * HID * 2;      // 25.6 MB
    __half* hp3   = (__half*)(base);                      // [3][N,256] fp16
    __half* emb16 = (__half*)(base + 3*PLANE);            // [3][N,256] fp16 (path-major)
    __half* h016  = (__half*)(base + 6*PLANE);            // [N,256] fp16
    char* small = base + 7*PLANE;
    float* ssrc3 = (float*)small;                          // 3*N*8 f32
    float* sdst3 = ssrc3 + 3*(size_t)N_NODES*NH;
    int*   cnt3  = (int*)(sdst3 + 3*(size_t)N_NODES*NH);   // 3*N int
    unsigned short* WT = (unsigned short*)(cnt3 + 3*N_NODES); // 9*131072 shorts
    unsigned short* slots3 = WT + 9*131072;                // 3*N*MAXD ushort
    float* w4 = (float*)(slots3 + (size_t)3*N_NODES*MAXD); // [N][4] f32 (raw scores)

    dim3 blk(256);
    const int gx = (N_NODES + 127) / 128;     // 391

    // weights + cnt3 zero in one dispatch (y=10 planes)
    cvtWall_k<<<dim3(256, 10), blk, 0, stream>>>(gatW, projW, semW1, clsW1, WT, cnt3);

    // proj union: fill edges [0, PROJ_EB) FIRST + h016 = fp16(x@projW+b)
    mfma_gemm_k<256,0,2,0,1><<<dim3(gx + PROJ_FB, 2), blk, 0, stream>>>(
        x, nullptr, 128, WT + 6*131072, WT + 6*131072 + 65536, projb,
        nullptr, h016, 256, N_NODES, 128, edges, cnt3, slots3, nullptr, 0, 0,
        nullptr, nullptr);

    // gemm3 l=0 union: fill edges [PROJ_EB, 3E) FIRST + GEMM (+ attn scores)
    mfma_gemm3_k<1><<<dim3(gx + G3_FB, 2, 3), blk, 0, stream>>>(
        h016, 0, HID, WT, 0, hp3, N_NODES, edges, cnt3, slots3,
        gatAs, gatAd, ssrc3, sdst3);

    // agg l=0, all paths (standalone: 0 LDS, high occupancy)
    agg3y_k<<<dim3(AGGB, 3), blk, 0, stream>>>(
        cnt3, slots3, ssrc3, sdst3, hp3, gatB, 0, emb16);

    // gemm3 l=1 (all paths): reads path-major emb16, writes hp3 + l=1 scores
    mfma_gemm3_k<0><<<dim3(gx, 2, 3), blk, 0, stream>>>(
        emb16, (int)((size_t)N_NODES*HID), HID, WT, 1, hp3, N_NODES,
        nullptr, nullptr, nullptr, gatAs, gatAd, ssrc3, sdst3);

    // agg l=1, all paths
    agg3y_k<<<dim3(AGGB, 3), blk, 0, stream>>>(
        cnt3, slots3, ssrc3, sdst3, hp3, gatB, 1, emb16);

    // semantic GEMMs, 3 paths in ONE dispatch (z = path); OUTMODE=4 fuses
    // tanh + dot(semW2) in the epilogue -> writes raw sc[n*4+p]
    mfma_gemm_k<128,1,4,1,0><<<dim3(gx, 1, 3), blk, 0, stream>>>(
        nullptr, emb16, 256, WT + 7*131072, WT + 7*131072 + 65536, semb1,
        w4, nullptr, 0, N_NODES, 256, nullptr, nullptr, nullptr, nullptr,
        (int)((size_t)N_NODES*HID), 1, semW2, nullptr);

    // classifier: inline softmax(w4 raw scores) -> on-the-fly z, relu +
    // logits fused in epilogue -> writes out[n][2] directly
    mfma_gemm_k<128,2,3,3,0><<<dim3(gx, 1), blk, 0, stream>>>(
        nullptr, emb16, HID, WT + 8*131072, WT + 8*131072 + 65536, clsb1,
        out, nullptr, 0, N_NODES, 256, nullptr, nullptr, nullptr, w4, 0, 0,
        clsW2, clsb2);
}